// Round 3
// baseline (501.041 us; speedup 1.0000x reference)
//
#include <hip/hip_runtime.h>
#include <hip/hip_bf16.h>
#include <math.h>

#define N_SAMPLES 262144
#define DDIM 64
#define KDIM 64
#define NBLOCKS 4096          // 4096 blocks x 4 waves x 16 rows (R1 grid)
#define NPART NBLOCKS         // one partial per BLOCK now

#define LOG2PI 1.8378770664093453f
#define PRIOR_LV0 -2.0f
#define IV0 7.389056098930650f  /* exp(2.0) */

// ws layout (floats):
//   [0, 4096)        : Bsw — 16 KB bf16 MFMA coef fragments
//                      frag-set s = kc*4+tile; lane l: 8 bf16 =
//                      B[kc*32 + (l>>4)*8 + j][tile*16 + (l&15)], j=0..7
//                      B[r][k] = r<64 ? P'[k][d=r] : Q[k][d=r-64]
//   [4096, 4160)     : c[k]            (lp bias)
//   [4160, 4224)     : c[k] + logpi[k] (LSE bias, fused)
//   [4224, 4224+NPART): per-block LSE partials (agent-scope stores)
//   [WS_KL]          : kl_phi * N  (written by setup)
//   [WS_TICKET]      : completion ticket (zeroed by setup, agent atomics)

#define WS_C      4096
#define WS_CL     4160
#define WS_PART   4224
#define WS_KL     (WS_PART + NPART)
#define WS_TICKET (WS_KL + 1)

typedef __attribute__((ext_vector_type(8))) short short8;
typedef __attribute__((ext_vector_type(4))) float floatx4;

static __device__ inline unsigned short f2bf_bits(float f) {
  union { float f; unsigned u; } v; v.f = f;
  unsigned r = v.u + 0x7fffu + ((v.u >> 16) & 1u);  // RNE
  return (unsigned short)(r >> 16);
}

__global__ __launch_bounds__(256) void setup_frags(
    const float* __restrict__ u_noise, const float* __restrict__ phi_logits,
    const float* __restrict__ q_mu, const float* __restrict__ q_logvar,
    const float* __restrict__ pi_logits, const float* __restrict__ prior_p,
    float* __restrict__ out, float* __restrict__ ws) {
  __shared__ float sPhi[DDIM];
  __shared__ float sR[DDIM];
  __shared__ float sLpi[KDIM];
  __shared__ float sBeta;
  __shared__ float sPart[4][KDIM];
  int tid = threadIdx.x;

  if (tid == 0) *(unsigned*)(ws + WS_TICKET) = 0u;  // reset ticket each iter

  if (tid < 64) {  // exactly wave 0
    int d = tid;
    float u = u_noise[d];
    float g = -__logf(-__logf(u + 1e-9f) + 1e-9f);
    float phi = 1.0f / (1.0f + __expf(-(phi_logits[d] + g)));  // TEMP=1
    sPhi[d] = phi;
    sR[d] = -0.5f * (1.0f - phi) * IV0;

    float betap = -0.5f * (1.0f - phi) * (LOG2PI + PRIOR_LV0);
    #pragma unroll
    for (int o = 1; o < 64; o <<= 1) betap += __shfl_xor(betap, o, 64);
    if (d == 0) sBeta = betap;

    // log(softmax(pi_logits) + 1e-9)
    float l = pi_logits[d];
    float m = l;
    #pragma unroll
    for (int o = 1; o < 64; o <<= 1) m = fmaxf(m, __shfl_xor(m, o, 64));
    float e = __expf(l - m);
    float s = e;
    #pragma unroll
    for (int o = 1; o < 64; o <<= 1) s += __shfl_xor(s, o, 64);
    sLpi[d] = __logf(e / s + 1e-9f);
  } else if (tid >= 64 && tid < 128) {  // wave 1: q_phi + kl_phi
    int d = tid - 64;
    float qp = 1.0f / (1.0f + __expf(-phi_logits[d]));
    qp = fminf(fmaxf(qp, 1e-6f), 1.0f - 1e-6f);
    out[1 + d] = qp;
    float pp = fminf(fmaxf(prior_p[d], 1e-6f), 1.0f - 1e-6f);
    float klp = qp * (__logf(qp) - __logf(pp)) +
                (1.0f - qp) * (__logf(1.0f - qp) - __logf(1.0f - pp));
    #pragma unroll
    for (int o = 1; o < 64; o <<= 1) klp += __shfl_xor(klp, o, 64);
    if (d == 0) ws[WS_KL] = klp * (float)N_SAMPLES;
  }
  __syncthreads();

  // c_k partials (256 threads: k = tid&63, d-segment = tid>>6)
  {
    int k = tid & 63, seg = tid >> 6;
    const float* lvp = q_logvar + k * DDIM + seg * 16;
    const float* mup = q_mu + k * DDIM + seg * 16;
    float ap = 0.0f;
    #pragma unroll
    for (int dd = 0; dd < 16; ++dd) {
      int d = seg * 16 + dd;
      float lv = fminf(fmaxf(lvp[dd], -5.0f), 5.0f);
      float mu = mup[dd];
      ap += sPhi[d] * (LOG2PI + lv) + mu * mu * sPhi[d] * __expf(-lv);
    }
    sPart[seg][k] = ap;
  }

  // B-fragments built directly from params
  unsigned short* bsw = (unsigned short*)ws;
  #pragma unroll
  for (int p = 0; p < 4; ++p) {
    int pr = p * 256 + tid;      // 0..1023 = frag-set*64 + lane
    int s = pr >> 6, l = pr & 63;
    int kc = s >> 2, tl = s & 3, q = l >> 4, nn = l & 15;
    int k = tl * 16 + nn;
    int dbase = (kc & 1) * 32 + q * 8;
    const float* lvp = q_logvar + k * DDIM + dbase;
    float4 lv0 = *(const float4*)lvp;
    float4 lv1 = *(const float4*)(lvp + 4);
    float lvv[8] = {lv0.x, lv0.y, lv0.z, lv0.w, lv1.x, lv1.y, lv1.z, lv1.w};
    short r8[8];
    if (kc < 2) {  // P' rows
      #pragma unroll
      for (int j = 0; j < 8; ++j) {
        int d = dbase + j;
        float lv = fminf(fmaxf(lvv[j], -5.0f), 5.0f);
        r8[j] = (short)f2bf_bits(-0.5f * sPhi[d] * __expf(-lv) + sR[d]);
      }
    } else {       // Q rows
      const float* mup = q_mu + k * DDIM + dbase;
      float4 mu0 = *(const float4*)mup;
      float4 mu1 = *(const float4*)(mup + 4);
      float muv[8] = {mu0.x, mu0.y, mu0.z, mu0.w, mu1.x, mu1.y, mu1.z, mu1.w};
      #pragma unroll
      for (int j = 0; j < 8; ++j) {
        int d = dbase + j;
        float lv = fminf(fmaxf(lvv[j], -5.0f), 5.0f);
        r8[j] = (short)f2bf_bits(muv[j] * sPhi[d] * __expf(-lv));
      }
    }
    ((short8*)bsw)[pr] = (short8){r8[0], r8[1], r8[2], r8[3],
                                  r8[4], r8[5], r8[6], r8[7]};
  }

  __syncthreads();
  if (tid < 64) {
    float alpha = sPart[0][tid] + sPart[1][tid] + sPart[2][tid] + sPart[3][tid];
    float c = -0.5f * alpha + sBeta;  // c_k
    ws[WS_C + tid] = c;
    ws[WS_CL + tid] = c + sLpi[tid];  // c_k + log pi_k
  }
}

// Main kernel: R1 grid (4096 blocks x 4 waves, one 16-row tile per wave),
// with the B coef table + bias tables staged in LDS once per block
// (kills the 1 GB of L2 B-fragment re-reads that serialized R1), and the
// final reduction merged in via a last-block ticket (agent-scope atomics
// for cross-XCD visibility).
__global__ __launch_bounds__(256, 8) void gmm_main(
    const float* __restrict__ X, float* __restrict__ ws,
    float* __restrict__ out) {
  __shared__ short8 sB[1024];     // 16 KB: 16 frag-sets x 64 lanes
  __shared__ float sCB[KDIM];     // c_k
  __shared__ float sCL[KDIM];     // c_k + log pi_k
  __shared__ float sW[4];
  __shared__ int sLast;
  int tid  = threadIdx.x;
  int lane = tid & 63;
  int w    = tid >> 6;
  int n    = lane & 15;   // sample within tile == C/D column
  int q    = lane >> 4;   // quad: C/D rows (clusters) q*4..q*4+3
  long rbase = ((long)blockIdx.x * 4 + w) * 16;

  // ---- X loads issued first (independent of LDS staging; hide HBM latency)
  const float* xr = X + (rbase + n) * DDIM + q * 8;
  float4 xa0 = *(const float4*)(xr);
  float4 xa1 = *(const float4*)(xr + 4);
  float4 xb0 = *(const float4*)(xr + 32);
  float4 xb1 = *(const float4*)(xr + 36);

  // ---- stage B frags + bias tables into LDS (once per block)
  {
    const short8* Bf = (const short8*)ws;
    #pragma unroll
    for (int p = 0; p < 4; ++p) sB[p * 256 + tid] = Bf[p * 256 + tid];
    if (tid < KDIM) { sCB[tid] = ws[WS_C + tid]; sCL[tid] = ws[WS_CL + tid]; }
  }
  __syncthreads();

  // ---- X fragments: kc0 = x^2 lo, kc1 = x^2 hi, kc2 = x lo, kc3 = x hi
  short8 a[4];
  {
    float xa[8] = {xa0.x, xa0.y, xa0.z, xa0.w, xa1.x, xa1.y, xa1.z, xa1.w};
    float xb[8] = {xb0.x, xb0.y, xb0.z, xb0.w, xb1.x, xb1.y, xb1.z, xb1.w};
    #pragma unroll
    for (int j = 0; j < 8; ++j) {
      a[0][j] = (short)f2bf_bits(xa[j] * xa[j]);
      a[1][j] = (short)f2bf_bits(xb[j] * xb[j]);
      a[2][j] = (short)f2bf_bits(xa[j]);
      a[3][j] = (short)f2bf_bits(xb[j]);
    }
  }

  // ---- MFMA: coef frags (LDS) as A, X frags as B -> D[cluster][sample]
  floatx4 acc[4];
  #pragma unroll
  for (int t = 0; t < 4; ++t) acc[t] = (floatx4){0.f, 0.f, 0.f, 0.f};
  #pragma unroll
  for (int kc = 0; kc < 4; ++kc) {
    #pragma unroll
    for (int t = 0; t < 4; ++t) {
      short8 b = sB[(kc * 4 + t) * 64 + lane];
      acc[t] = __builtin_amdgcn_mfma_f32_16x16x32_bf16(b, a[kc], acc[t], 0, 0, 0);
    }
  }

  // ---- epilogue: bias + 16B store per tile-col + lane-local LSE
  float* lp = out + 1 + DDIM;           // float-offset 65
  long rowoff = (rbase + n) * KDIM;
  #pragma unroll
  for (int t = 0; t < 4; ++t) {
    float4 cb = *(const float4*)&sCB[t * 16 + q * 4];
    float4 cl = *(const float4*)&sCL[t * 16 + q * 4];
    float o4[4];
    o4[0] = acc[t][0] + cb.x;
    o4[1] = acc[t][1] + cb.y;
    o4[2] = acc[t][2] + cb.z;
    o4[3] = acc[t][3] + cb.w;
    // 16B store at 4B alignment (gfx950 unaligned global access)
    __builtin_memcpy(lp + rowoff + t * 16 + q * 4, o4, 16);
    acc[t][0] += cl.x;
    acc[t][1] += cl.y;
    acc[t][2] += cl.z;
    acc[t][3] += cl.w;
  }

  float m = acc[0][0];
  #pragma unroll
  for (int t = 0; t < 4; ++t)
    #pragma unroll
    for (int r = 0; r < 4; ++r) m = fmaxf(m, acc[t][r]);
  m = fmaxf(m, __shfl_xor(m, 16, 64));
  m = fmaxf(m, __shfl_xor(m, 32, 64));

  float s = 0.0f;
  #pragma unroll
  for (int t = 0; t < 4; ++t)
    #pragma unroll
    for (int r = 0; r < 4; ++r) s += __expf(acc[t][r] - m);
  s += __shfl_xor(s, 16, 64);
  s += __shfl_xor(s, 32, 64);

  float lse = m + __logf(s);  // per-sample; identical across q-groups
  lse += __shfl_xor(lse, 1, 64);
  lse += __shfl_xor(lse, 2, 64);
  lse += __shfl_xor(lse, 4, 64);
  lse += __shfl_xor(lse, 8, 64);
  if (lane == 0) sW[w] = lse;
  __syncthreads();

  // ---- last-block finalize (ticket; agent scope for cross-XCD visibility)
  if (tid == 0) {
    float part = sW[0] + sW[1] + sW[2] + sW[3];
    __hip_atomic_store(&ws[WS_PART + blockIdx.x], part,
                       __ATOMIC_RELEASE, __HIP_MEMORY_SCOPE_AGENT);
    unsigned old = __hip_atomic_fetch_add((unsigned*)(ws + WS_TICKET), 1u,
                                          __ATOMIC_ACQ_REL,
                                          __HIP_MEMORY_SCOPE_AGENT);
    sLast = (old == NBLOCKS - 1) ? 1 : 0;
  }
  __syncthreads();

  if (sLast) {
    float t2 = 0.0f;
    #pragma unroll
    for (int i = 0; i < NPART / 256; ++i)
      t2 += __hip_atomic_load(&ws[WS_PART + i * 256 + tid],
                              __ATOMIC_RELAXED, __HIP_MEMORY_SCOPE_AGENT);
    #pragma unroll
    for (int o = 1; o < 64; o <<= 1) t2 += __shfl_xor(t2, o, 64);
    __syncthreads();           // sW reuse barrier
    if (lane == 0) sW[w] = t2;
    __syncthreads();
    if (tid == 0) out[0] = ws[WS_KL] - (sW[0] + sW[1] + sW[2] + sW[3]);
  }
}

extern "C" void kernel_launch(void* const* d_in, const int* in_sizes, int n_in,
                              void* d_out, int out_size, void* d_ws, size_t ws_size,
                              hipStream_t stream) {
  const float* X           = (const float*)d_in[0];
  const float* u_noise     = (const float*)d_in[1];
  const float* phi_logits  = (const float*)d_in[2];
  const float* q_mu        = (const float*)d_in[3];
  const float* q_logvar    = (const float*)d_in[4];
  const float* pi_logits   = (const float*)d_in[5];
  const float* prior_p     = (const float*)d_in[6];
  float* out = (float*)d_out;
  float* ws  = (float*)d_ws;

  setup_frags<<<1, 256, 0, stream>>>(u_noise, phi_logits, q_mu, q_logvar,
                                     pi_logits, prior_p, out, ws);
  gmm_main<<<NBLOCKS, 256, 0, stream>>>(X, ws, out);
}

// Round 4
// 137.771 us; speedup vs baseline: 3.6368x; 3.6368x over previous
//
#include <hip/hip_runtime.h>
#include <hip/hip_bf16.h>
#include <math.h>

#define N_SAMPLES 262144
#define DDIM 64
#define KDIM 64
#define NBLOCKS 4096          // 4096 blocks x 4 waves x 16 rows (R1 grid)
#define NPART (NBLOCKS * 4)   // one partial per wave

#define LOG2PI 1.8378770664093453f
#define PRIOR_LV0 -2.0f
#define IV0 7.389056098930650f  /* exp(2.0) */

// ws layout (floats):
//   [0, 4096)        : Bsw — 16 KB bf16 MFMA coef fragments
//                      frag-set s = kc*4+tile; lane l: 8 bf16 =
//                      B[kc*32 + (l>>4)*8 + j][tile*16 + (l&15)], j=0..7
//                      B[r][k] = r<64 ? P'[k][d=r] : Q[k][d=r-64]
//                      (same bits serve as the A-operand of the swapped
//                       mfma: A[m=cluster][k=d] fragment)
//   [4096, 4160)     : c[k]            (lp bias)
//   [4160, 4224)     : c[k] + logpi[k] (LSE bias, fused)
//   [4224, 4224+NPART): per-wave LSE partials (plain stores)
//   [WS_KL]          : kl_phi * N  (written by setup)

#define WS_C      4096
#define WS_CL     4160
#define WS_PART   4224
#define WS_KL     (WS_PART + NPART)

typedef __attribute__((ext_vector_type(8))) short short8;
typedef __attribute__((ext_vector_type(4))) float floatx4;

static __device__ inline unsigned short f2bf_bits(float f) {
  union { float f; unsigned u; } v; v.f = f;
  unsigned r = v.u + 0x7fffu + ((v.u >> 16) & 1u);  // RNE
  return (unsigned short)(r >> 16);
}

__global__ __launch_bounds__(256) void setup_frags(
    const float* __restrict__ u_noise, const float* __restrict__ phi_logits,
    const float* __restrict__ q_mu, const float* __restrict__ q_logvar,
    const float* __restrict__ pi_logits, const float* __restrict__ prior_p,
    float* __restrict__ out, float* __restrict__ ws) {
  __shared__ float sPhi[DDIM];
  __shared__ float sR[DDIM];
  __shared__ float sLpi[KDIM];
  __shared__ float sBeta;
  __shared__ float sPart[4][KDIM];
  int tid = threadIdx.x;

  if (tid < 64) {  // exactly wave 0
    int d = tid;
    float u = u_noise[d];
    float g = -__logf(-__logf(u + 1e-9f) + 1e-9f);
    float phi = 1.0f / (1.0f + __expf(-(phi_logits[d] + g)));  // TEMP=1
    sPhi[d] = phi;
    sR[d] = -0.5f * (1.0f - phi) * IV0;

    float betap = -0.5f * (1.0f - phi) * (LOG2PI + PRIOR_LV0);
    #pragma unroll
    for (int o = 1; o < 64; o <<= 1) betap += __shfl_xor(betap, o, 64);
    if (d == 0) sBeta = betap;

    // log(softmax(pi_logits) + 1e-9)
    float l = pi_logits[d];
    float m = l;
    #pragma unroll
    for (int o = 1; o < 64; o <<= 1) m = fmaxf(m, __shfl_xor(m, o, 64));
    float e = __expf(l - m);
    float s = e;
    #pragma unroll
    for (int o = 1; o < 64; o <<= 1) s += __shfl_xor(s, o, 64);
    sLpi[d] = __logf(e / s + 1e-9f);
  } else if (tid >= 64 && tid < 128) {  // wave 1: q_phi + kl_phi
    int d = tid - 64;
    float qp = 1.0f / (1.0f + __expf(-phi_logits[d]));
    qp = fminf(fmaxf(qp, 1e-6f), 1.0f - 1e-6f);
    out[1 + d] = qp;
    float pp = fminf(fmaxf(prior_p[d], 1e-6f), 1.0f - 1e-6f);
    float klp = qp * (__logf(qp) - __logf(pp)) +
                (1.0f - qp) * (__logf(1.0f - qp) - __logf(1.0f - pp));
    #pragma unroll
    for (int o = 1; o < 64; o <<= 1) klp += __shfl_xor(klp, o, 64);
    if (d == 0) ws[WS_KL] = klp * (float)N_SAMPLES;
  }
  __syncthreads();

  // c_k partials (256 threads: k = tid&63, d-segment = tid>>6)
  {
    int k = tid & 63, seg = tid >> 6;
    const float* lvp = q_logvar + k * DDIM + seg * 16;
    const float* mup = q_mu + k * DDIM + seg * 16;
    float ap = 0.0f;
    #pragma unroll
    for (int dd = 0; dd < 16; ++dd) {
      int d = seg * 16 + dd;
      float lv = fminf(fmaxf(lvp[dd], -5.0f), 5.0f);
      float mu = mup[dd];
      ap += sPhi[d] * (LOG2PI + lv) + mu * mu * sPhi[d] * __expf(-lv);
    }
    sPart[seg][k] = ap;
  }

  // B-fragments built directly from params
  unsigned short* bsw = (unsigned short*)ws;
  #pragma unroll
  for (int p = 0; p < 4; ++p) {
    int pr = p * 256 + tid;      // 0..1023 = frag-set*64 + lane
    int s = pr >> 6, l = pr & 63;
    int kc = s >> 2, tl = s & 3, q = l >> 4, nn = l & 15;
    int k = tl * 16 + nn;
    int dbase = (kc & 1) * 32 + q * 8;
    const float* lvp = q_logvar + k * DDIM + dbase;
    float4 lv0 = *(const float4*)lvp;
    float4 lv1 = *(const float4*)(lvp + 4);
    float lvv[8] = {lv0.x, lv0.y, lv0.z, lv0.w, lv1.x, lv1.y, lv1.z, lv1.w};
    short r8[8];
    if (kc < 2) {  // P' rows
      #pragma unroll
      for (int j = 0; j < 8; ++j) {
        int d = dbase + j;
        float lv = fminf(fmaxf(lvv[j], -5.0f), 5.0f);
        r8[j] = (short)f2bf_bits(-0.5f * sPhi[d] * __expf(-lv) + sR[d]);
      }
    } else {       // Q rows
      const float* mup = q_mu + k * DDIM + dbase;
      float4 mu0 = *(const float4*)mup;
      float4 mu1 = *(const float4*)(mup + 4);
      float muv[8] = {mu0.x, mu0.y, mu0.z, mu0.w, mu1.x, mu1.y, mu1.z, mu1.w};
      #pragma unroll
      for (int j = 0; j < 8; ++j) {
        int d = dbase + j;
        float lv = fminf(fmaxf(lvv[j], -5.0f), 5.0f);
        r8[j] = (short)f2bf_bits(muv[j] * sPhi[d] * __expf(-lv));
      }
    }
    ((short8*)bsw)[pr] = (short8){r8[0], r8[1], r8[2], r8[3],
                                  r8[4], r8[5], r8[6], r8[7]};
  }

  __syncthreads();
  if (tid < 64) {
    float alpha = sPart[0][tid] + sPart[1][tid] + sPart[2][tid] + sPart[3][tid];
    float c = -0.5f * alpha + sBeta;  // c_k
    ws[WS_C + tid] = c;
    ws[WS_CL + tid] = c + sLpi[tid];  // c_k + log pi_k
  }
}

// Main kernel: R1 grid (4096 blocks x 4 waves, one 16-row tile per wave),
// B coef table + bias tables staged in LDS once per block — kills the
// ~1 GB of L2 B-fragment re-reads that bounded R1. No atomics, no
// cross-block sync; per-wave partial via plain store (finalize kernel
// reduces them).
__global__ __launch_bounds__(256, 8) void gmm_main(
    const float* __restrict__ X, float* __restrict__ ws,
    float* __restrict__ out) {
  __shared__ short8 sB[1024];     // 16 KB: 16 frag-sets x 64 lanes
  __shared__ float sCB[KDIM];     // c_k
  __shared__ float sCL[KDIM];     // c_k + log pi_k
  int tid  = threadIdx.x;
  int lane = tid & 63;
  int w    = tid >> 6;
  int n    = lane & 15;   // sample within tile == C/D column
  int q    = lane >> 4;   // quad: C/D rows (clusters) q*4..q*4+3
  long rbase = ((long)blockIdx.x * 4 + w) * 16;

  // ---- X loads issued first (independent of LDS staging; hide HBM latency)
  const float* xr = X + (rbase + n) * DDIM + q * 8;
  float4 xa0 = *(const float4*)(xr);
  float4 xa1 = *(const float4*)(xr + 4);
  float4 xb0 = *(const float4*)(xr + 32);
  float4 xb1 = *(const float4*)(xr + 36);

  // ---- stage B frags + bias tables into LDS (once per block)
  {
    const short8* Bf = (const short8*)ws;
    #pragma unroll
    for (int p = 0; p < 4; ++p) sB[p * 256 + tid] = Bf[p * 256 + tid];
    if (tid < KDIM) { sCB[tid] = ws[WS_C + tid]; sCL[tid] = ws[WS_CL + tid]; }
  }
  __syncthreads();

  // ---- X fragments: kc0 = x^2 lo, kc1 = x^2 hi, kc2 = x lo, kc3 = x hi
  short8 a[4];
  {
    float xa[8] = {xa0.x, xa0.y, xa0.z, xa0.w, xa1.x, xa1.y, xa1.z, xa1.w};
    float xb[8] = {xb0.x, xb0.y, xb0.z, xb0.w, xb1.x, xb1.y, xb1.z, xb1.w};
    #pragma unroll
    for (int j = 0; j < 8; ++j) {
      a[0][j] = (short)f2bf_bits(xa[j] * xa[j]);
      a[1][j] = (short)f2bf_bits(xb[j] * xb[j]);
      a[2][j] = (short)f2bf_bits(xa[j]);
      a[3][j] = (short)f2bf_bits(xb[j]);
    }
  }

  // ---- MFMA: coef frags (LDS) as A, X frags as B -> D[cluster][sample]
  floatx4 acc[4];
  #pragma unroll
  for (int t = 0; t < 4; ++t) acc[t] = (floatx4){0.f, 0.f, 0.f, 0.f};
  #pragma unroll
  for (int kc = 0; kc < 4; ++kc) {
    #pragma unroll
    for (int t = 0; t < 4; ++t) {
      short8 b = sB[(kc * 4 + t) * 64 + lane];
      acc[t] = __builtin_amdgcn_mfma_f32_16x16x32_bf16(b, a[kc], acc[t], 0, 0, 0);
    }
  }

  // ---- epilogue: bias + 16B store per tile-col + lane-local LSE
  float* lp = out + 1 + DDIM;           // float-offset 65
  long rowoff = (rbase + n) * KDIM;
  #pragma unroll
  for (int t = 0; t < 4; ++t) {
    float4 cb = *(const float4*)&sCB[t * 16 + q * 4];
    float4 cl = *(const float4*)&sCL[t * 16 + q * 4];
    float o4[4];
    o4[0] = acc[t][0] + cb.x;
    o4[1] = acc[t][1] + cb.y;
    o4[2] = acc[t][2] + cb.z;
    o4[3] = acc[t][3] + cb.w;
    // 16B store at 4B alignment (gfx950 unaligned global access)
    __builtin_memcpy(lp + rowoff + t * 16 + q * 4, o4, 16);
    acc[t][0] += cl.x;
    acc[t][1] += cl.y;
    acc[t][2] += cl.z;
    acc[t][3] += cl.w;
  }

  float m = acc[0][0];
  #pragma unroll
  for (int t = 0; t < 4; ++t)
    #pragma unroll
    for (int r = 0; r < 4; ++r) m = fmaxf(m, acc[t][r]);
  m = fmaxf(m, __shfl_xor(m, 16, 64));
  m = fmaxf(m, __shfl_xor(m, 32, 64));

  float s = 0.0f;
  #pragma unroll
  for (int t = 0; t < 4; ++t)
    #pragma unroll
    for (int r = 0; r < 4; ++r) s += __expf(acc[t][r] - m);
  s += __shfl_xor(s, 16, 64);
  s += __shfl_xor(s, 32, 64);

  float lse = m + __logf(s);  // per-sample; identical across q-groups
  lse += __shfl_xor(lse, 1, 64);
  lse += __shfl_xor(lse, 2, 64);
  lse += __shfl_xor(lse, 4, 64);
  lse += __shfl_xor(lse, 8, 64);
  if (lane == 0) ws[WS_PART + blockIdx.x * 4 + w] = lse;
}

// Final: sum per-wave partials, combine with kl from ws.
__global__ __launch_bounds__(256) void finalize_kernel(
    const float* __restrict__ ws, float* __restrict__ out) {
  __shared__ float sW[4];
  int tid = threadIdx.x;
  int lane = tid & 63, w = tid >> 6;

  float s = 0.0f;
  #pragma unroll
  for (int i = 0; i < NPART / 256; ++i)
    s += ws[WS_PART + i * 256 + tid];
  #pragma unroll
  for (int o = 1; o < 64; o <<= 1) s += __shfl_xor(s, o, 64);
  if (lane == 0) sW[w] = s;
  __syncthreads();
  if (tid == 0) out[0] = ws[WS_KL] - (sW[0] + sW[1] + sW[2] + sW[3]);
}

extern "C" void kernel_launch(void* const* d_in, const int* in_sizes, int n_in,
                              void* d_out, int out_size, void* d_ws, size_t ws_size,
                              hipStream_t stream) {
  const float* X           = (const float*)d_in[0];
  const float* u_noise     = (const float*)d_in[1];
  const float* phi_logits  = (const float*)d_in[2];
  const float* q_mu        = (const float*)d_in[3];
  const float* q_logvar    = (const float*)d_in[4];
  const float* pi_logits   = (const float*)d_in[5];
  const float* prior_p     = (const float*)d_in[6];
  float* out = (float*)d_out;
  float* ws  = (float*)d_ws;

  setup_frags<<<1, 256, 0, stream>>>(u_noise, phi_logits, q_mu, q_logvar,
                                     pi_logits, prior_p, out, ws);
  gmm_main<<<NBLOCKS, 256, 0, stream>>>(X, ws, out);
  finalize_kernel<<<1, 256, 0, stream>>>(ws, out);
}